// Round 1
// baseline (2329.179 us; speedup 1.0000x reference)
//
#include <hip/hip_runtime.h>

#define H 4
#define C1 32
#define D1 128
#define C2 64
#define D2 256
#define CIN 16
#define SLOPE 0.2f

// ---- float <-> order-preserving uint encoding (for atomicMax on floats) ----
__device__ __forceinline__ unsigned int enc_f(float f) {
    unsigned int u = __float_as_uint(f);
    return (u & 0x80000000u) ? ~u : (u | 0x80000000u);
}
__device__ __forceinline__ float dec_f(unsigned int e) {
    return (e & 0x80000000u) ? __uint_as_float(e & 0x7FFFFFFFu)
                             : __uint_as_float(~e);
}

// ---- layer-1 linear: normalize x, compute xl = yW1l+b1l, xr = yW1r+b1r ----
__global__ void k_lin1(const float* __restrict__ x, const float* __restrict__ lb,
                       const float* __restrict__ ub,
                       const float* __restrict__ Wl, const float* __restrict__ bl,
                       const float* __restrict__ Wr, const float* __restrict__ br,
                       float* __restrict__ xl, float* __restrict__ xr) {
    __shared__ float ys[CIN];
    int i = blockIdx.x;
    int t = threadIdx.x;
    if (t < CIN) ys[t] = (x[i * CIN + t] - lb[t]) / (ub[t] - lb[t]);
    __syncthreads();
    float al = bl[t], ar = br[t];
#pragma unroll
    for (int k = 0; k < CIN; ++k) {
        float yv = ys[k];
        al += yv * Wl[k * D1 + t];
        ar += yv * Wr[k * D1 + t];
    }
    xl[(size_t)i * D1 + t] = al;
    xr[(size_t)i * D1 + t] = ar;
}

// ---- layer-2 linear: xl2 = h1 W2l + b2l, xr2 = h1 W2r + b2r ----
__global__ void k_lin2(const float* __restrict__ h1,
                       const float* __restrict__ Wl, const float* __restrict__ bl,
                       const float* __restrict__ Wr, const float* __restrict__ br,
                       float* __restrict__ xl, float* __restrict__ xr) {
    __shared__ float hs[D1];
    int i = blockIdx.x;
    int t = threadIdx.x;  // 256 threads
    if (t < D1) hs[t] = h1[(size_t)i * D1 + t];
    __syncthreads();
    float al = bl[t], ar = br[t];
#pragma unroll 8
    for (int k = 0; k < D1; ++k) {
        float hv = hs[k];
        al += hv * Wl[k * D2 + t];
        ar += hv * Wr[k * D2 + t];
    }
    xl[(size_t)i * D2 + t] = al;
    xr[(size_t)i * D2 + t] = ar;
}

// ---- edge logits: per (edge, head): att . leaky_relu(xl[src]+xr[dst]); atomicMax per dst ----
__global__ void k_logits(const float* __restrict__ xl, const float* __restrict__ xr,
                         const float* __restrict__ att, const int* __restrict__ ei,
                         int E, int ET, int C, int D,
                         float* __restrict__ elog, unsigned int* __restrict__ menc) {
    long long idx = (long long)blockIdx.x * blockDim.x + threadIdx.x;
    if (idx >= (long long)ET * H) return;
    int e = (int)(idx >> 2);
    int h = (int)(idx & 3);
    int src, dst;
    if (e < E) { src = ei[e]; dst = ei[E + e]; }
    else       { src = dst = e - E; }
    const float4* pl = (const float4*)(xl + (size_t)src * D + h * C);
    const float4* pr = (const float4*)(xr + (size_t)dst * D + h * C);
    const float4* pa = (const float4*)(att + h * C);
    float acc = 0.f;
    for (int c4 = 0; c4 < (C >> 2); ++c4) {
        float4 a = pl[c4], b = pr[c4], w = pa[c4];
        float v;
        v = a.x + b.x; v = v > 0.f ? v : SLOPE * v; acc += w.x * v;
        v = a.y + b.y; v = v > 0.f ? v : SLOPE * v; acc += w.y * v;
        v = a.z + b.z; v = v > 0.f ? v : SLOPE * v; acc += w.z * v;
        v = a.w + b.w; v = v > 0.f ? v : SLOPE * v; acc += w.w * v;
    }
    elog[idx] = acc;
    atomicMax(&menc[dst * 4 + h], enc_f(acc));
}

// ---- scatter: per (edge, component): acc[dst,p] += exp(logit-m) * xl[src,p]; s[dst,h] += ex ----
__global__ void k_scatter(const float* __restrict__ xl, const float* __restrict__ elog,
                          const unsigned int* __restrict__ menc, const int* __restrict__ ei,
                          int E, int ET, int dshift, int cshift,
                          float* __restrict__ outacc, float* __restrict__ s) {
    long long idx = (long long)blockIdx.x * blockDim.x + threadIdx.x;
    if (idx >= ((long long)ET << dshift)) return;
    int e = (int)(idx >> dshift);
    int p = (int)(idx & ((1 << dshift) - 1));
    int h = p >> cshift;
    int src, dst;
    if (e < E) { src = ei[e]; dst = ei[E + e]; }
    else       { src = dst = e - E; }
    float m = dec_f(menc[dst * 4 + h]);
    float ex = __expf(elog[e * 4 + h] - m);
    if ((p & ((1 << cshift) - 1)) == 0) atomicAdd(&s[dst * 4 + h], ex);
    int D = 1 << dshift;
    atomicAdd(&outacc[(size_t)dst * D + p], ex * xl[(size_t)src * D + p]);
}

// ---- finalize layer 1: h1 = relu(acc / s + bias1) ----
__global__ void k_fin1(float* __restrict__ h1, const float* __restrict__ s,
                       const float* __restrict__ b1) {
    int i = blockIdx.x;
    int t = threadIdx.x;  // 128
    int h = t >> 5;
    float v = h1[(size_t)i * D1 + t] / s[i * 4 + h] + b1[t];
    h1[(size_t)i * D1 + t] = v > 0.f ? v : 0.f;
}

// ---- finalize layer 2 + head: mean over heads, +bias2, relu, W3, sigmoid ----
__global__ void k_fin2(const float* __restrict__ o2, const float* __restrict__ s,
                       const float* __restrict__ b2,
                       const float* __restrict__ W3, const float* __restrict__ b3,
                       float* __restrict__ out) {
    __shared__ float hs[C2];
    int i = blockIdx.x;
    int t = threadIdx.x;  // 64
    float acc = 0.f;
#pragma unroll
    for (int h = 0; h < H; ++h)
        acc += o2[(size_t)i * D2 + h * C2 + t] / s[i * 4 + h];
    acc = acc * 0.25f + b2[t];
    hs[t] = acc > 0.f ? acc : 0.f;
    __syncthreads();
    if (t < 5) {
        float a = b3[t];
#pragma unroll 8
        for (int c = 0; c < C2; ++c) a += hs[c] * W3[c * 5 + t];
        out[(size_t)i * 5 + t] = 1.f / (1.f + __expf(-a));
    }
}

extern "C" void kernel_launch(void* const* d_in, const int* in_sizes, int n_in,
                              void* d_out, int out_size, void* d_ws, size_t ws_size,
                              hipStream_t stream) {
    const float* x     = (const float*)d_in[0];
    const int*   ei    = (const int*)d_in[1];
    const float* lb    = (const float*)d_in[2];
    const float* ub    = (const float*)d_in[3];
    const float* W1l   = (const float*)d_in[4];
    const float* b1l   = (const float*)d_in[5];
    const float* W1r   = (const float*)d_in[6];
    const float* b1r   = (const float*)d_in[7];
    const float* att1  = (const float*)d_in[8];
    const float* bias1 = (const float*)d_in[9];
    const float* W2l   = (const float*)d_in[10];
    const float* b2l   = (const float*)d_in[11];
    const float* W2r   = (const float*)d_in[12];
    const float* b2r   = (const float*)d_in[13];
    const float* att2  = (const float*)d_in[14];
    const float* bias2 = (const float*)d_in[15];
    const float* W3    = (const float*)d_in[16];
    const float* b3    = (const float*)d_in[17];

    int n  = in_sizes[0] / CIN;
    int E  = in_sizes[1] / 2;
    int ET = E + n;

    // workspace layout (aliased: xl2 reuses xl1|xr1 region)
    char* ws = (char*)d_ws;
    size_t off = 0;
    auto alloc = [&](size_t nbytes) {
        void* p = ws + off;
        off += (nbytes + 255) & ~(size_t)255;
        return p;
    };
    float* R0   = (float*)alloc((size_t)n * D2 * 4);  // xl1 | xr1 ; later xl2
    float* h1   = (float*)alloc((size_t)n * D1 * 4);  // layer-1 acc -> h1
    float* xr2  = (float*)alloc((size_t)n * D2 * 4);
    float* o2   = (float*)alloc((size_t)n * D2 * 4);
    unsigned int* menc = (unsigned int*)alloc((size_t)n * 4 * 4);
    float* sden = (float*)alloc((size_t)n * 4 * 4);
    float* elog = (float*)alloc((size_t)ET * 4 * 4);
    float* xl1 = R0;
    float* xr1 = R0 + (size_t)n * D1;
    float* xl2 = R0;

    // ---------- layer 1 ----------
    hipMemsetAsync(menc, 0, (size_t)n * 16, stream);
    hipMemsetAsync(sden, 0, (size_t)n * 16, stream);
    hipMemsetAsync(h1, 0, (size_t)n * D1 * 4, stream);

    k_lin1<<<n, D1, 0, stream>>>(x, lb, ub, W1l, b1l, W1r, b1r, xl1, xr1);

    {
        long long tot = (long long)ET * H;
        k_logits<<<(int)((tot + 255) / 256), 256, 0, stream>>>(
            xl1, xr1, att1, ei, E, ET, C1, D1, elog, menc);
        long long tot2 = (long long)ET * D1;
        k_scatter<<<(int)((tot2 + 255) / 256), 256, 0, stream>>>(
            xl1, elog, menc, ei, E, ET, 7, 5, h1, sden);
    }
    k_fin1<<<n, D1, 0, stream>>>(h1, sden, bias1);

    // ---------- layer 2 ----------
    hipMemsetAsync(menc, 0, (size_t)n * 16, stream);
    hipMemsetAsync(sden, 0, (size_t)n * 16, stream);
    hipMemsetAsync(o2, 0, (size_t)n * D2 * 4, stream);

    k_lin2<<<n, D2, 0, stream>>>(h1, W2l, b2l, W2r, b2r, xl2, xr2);

    {
        long long tot = (long long)ET * H;
        k_logits<<<(int)((tot + 255) / 256), 256, 0, stream>>>(
            xl2, xr2, att2, ei, E, ET, C2, D2, elog, menc);
        long long tot2 = (long long)ET * D2;
        k_scatter<<<(int)((tot2 + 255) / 256), 256, 0, stream>>>(
            xl2, elog, menc, ei, E, ET, 8, 6, o2, sden);
    }
    k_fin2<<<n, C2, 0, stream>>>(o2, sden, bias2, W3, b3, (float*)d_out);
}

// Round 2
// 615.048 us; speedup vs baseline: 3.7870x; 3.7870x over previous
//
#include <hip/hip_runtime.h>

#define H 4
#define C1 32
#define D1 128
#define C2 64
#define D2 256
#define CIN 16
#define SLOPE 0.2f

// ============ CSR build ============
__global__ void k_hist(const int* __restrict__ ei, int E, int ET,
                       int* __restrict__ deg) {
    int idx = blockIdx.x * blockDim.x + threadIdx.x;
    if (idx >= ET) return;
    int dst = (idx < E) ? ei[E + idx] : idx - E;
    atomicAdd(&deg[dst], 1);
}

__global__ void k_scan_block(const int* __restrict__ deg, int* __restrict__ rp,
                             int* __restrict__ bsum, int n) {
    __shared__ int s[256];
    int t = threadIdx.x, idx = blockIdx.x * 256 + t;
    int v = (idx < n) ? deg[idx] : 0;
    s[t] = v; __syncthreads();
    for (int off = 1; off < 256; off <<= 1) {
        int add = (t >= off) ? s[t - off] : 0;
        __syncthreads();
        s[t] += add;
        __syncthreads();
    }
    if (idx < n) rp[idx] = s[t] - v;          // block-local exclusive
    if (t == 255) bsum[blockIdx.x] = s[255];  // block total
}

__global__ void k_scan_top(int* __restrict__ bsum, int nb) {
    __shared__ int s[256];
    int t = threadIdx.x;
    int v = (t < nb) ? bsum[t] : 0;
    s[t] = v; __syncthreads();
    for (int off = 1; off < 256; off <<= 1) {
        int add = (t >= off) ? s[t - off] : 0;
        __syncthreads();
        s[t] += add;
        __syncthreads();
    }
    if (t < nb) bsum[t] = s[t] - v;           // exclusive over block totals
}

__global__ void k_scan_add(int* __restrict__ rp, const int* __restrict__ bsum, int n) {
    int idx = blockIdx.x * blockDim.x + threadIdx.x;
    if (idx < n) rp[idx] += bsum[idx >> 8];
}

__global__ void k_fill(const int* __restrict__ ei, int E, int ET,
                       const int* __restrict__ rp, int* __restrict__ cur,
                       int* __restrict__ eord) {
    int idx = blockIdx.x * blockDim.x + threadIdx.x;
    if (idx >= ET) return;
    int src, dst;
    if (idx < E) { src = ei[idx]; dst = ei[E + idx]; }
    else         { src = dst = idx - E; }
    int pos = atomicAdd(&cur[dst], 1);
    eord[rp[dst] + pos] = src;   // store src node id directly
}

// ============ dense linears ============
__global__ __launch_bounds__(D1) void k_lin1(
        const float* __restrict__ x, const float* __restrict__ lb,
        const float* __restrict__ ub,
        const float* __restrict__ Wl, const float* __restrict__ bl,
        const float* __restrict__ Wr, const float* __restrict__ br,
        float* __restrict__ xl, float* __restrict__ xr) {
    __shared__ float ys[CIN];
    int i = blockIdx.x, t = threadIdx.x;
    if (t < CIN) ys[t] = (x[i * CIN + t] - lb[t]) / (ub[t] - lb[t]);
    __syncthreads();
    float al = bl[t], ar = br[t];
#pragma unroll
    for (int k = 0; k < CIN; ++k) {
        float yv = ys[k];
        al += yv * Wl[k * D1 + t];
        ar += yv * Wr[k * D1 + t];
    }
    xl[(size_t)i * D1 + t] = al;
    xr[(size_t)i * D1 + t] = ar;
}

__global__ __launch_bounds__(D2) void k_lin2(
        const float* __restrict__ h1,
        const float* __restrict__ Wl, const float* __restrict__ bl,
        const float* __restrict__ Wr, const float* __restrict__ br,
        float* __restrict__ xl, float* __restrict__ xr) {
    __shared__ float hs[D1];
    int i = blockIdx.x, t = threadIdx.x;
    if (t < D1) hs[t] = h1[(size_t)i * D1 + t];
    __syncthreads();
    float al = bl[t], ar = br[t];
#pragma unroll 8
    for (int k = 0; k < D1; ++k) {
        float hv = hs[k];
        al += hv * Wl[k * D2 + t];
        ar += hv * Wr[k * D2 + t];
    }
    xl[(size_t)i * D2 + t] = al;
    xr[(size_t)i * D2 + t] = ar;
}

// ============ fused GATv2 aggregation, layer 1 ============
// block = node i, 128 threads; head h = t>>5 (32-lane groups); online softmax.
__global__ __launch_bounds__(D1) void k_agg1(
        const float* __restrict__ xl, const float* __restrict__ xr,
        const float* __restrict__ att, const float* __restrict__ bias,
        const int* __restrict__ rp, const int* __restrict__ deg,
        const int* __restrict__ eord, float* __restrict__ h1) {
    int i = blockIdx.x, t = threadIdx.x;
    float xrv  = xr[(size_t)i * D1 + t];
    float attv = att[t];
    int start = rp[i], cnt = deg[i];
    float m = -1e30f, d = 0.f, acc = 0.f;
    for (int j = 0; j < cnt; ++j) {
        int src = eord[start + j];
        float xlv = xl[(size_t)src * D1 + t];
        float v = xlv + xrv;
        v = v > 0.f ? v : SLOPE * v;
        float lg = attv * v;
        lg += __shfl_xor(lg, 16, 32);
        lg += __shfl_xor(lg,  8, 32);
        lg += __shfl_xor(lg,  4, 32);
        lg += __shfl_xor(lg,  2, 32);
        lg += __shfl_xor(lg,  1, 32);
        if (lg > m) { float sc = __expf(m - lg); d *= sc; acc *= sc; m = lg; }
        float ex = __expf(lg - m);
        d += ex;
        acc += ex * xlv;
    }
    float val = acc / d + bias[t];
    h1[(size_t)i * D1 + t] = val > 0.f ? val : 0.f;
}

// ============ fused GATv2 aggregation + head, layer 2 ============
// block = node i, 256 threads; head h = t>>6 (64-lane groups = full wave).
__global__ __launch_bounds__(D2) void k_agg2(
        const float* __restrict__ xl, const float* __restrict__ xr,
        const float* __restrict__ att, const float* __restrict__ b2,
        const float* __restrict__ W3, const float* __restrict__ b3,
        const int* __restrict__ rp, const int* __restrict__ deg,
        const int* __restrict__ eord, float* __restrict__ out) {
    __shared__ float sh[D2];
    int i = blockIdx.x, t = threadIdx.x;
    float xrv  = xr[(size_t)i * D2 + t];
    float attv = att[t];
    int start = rp[i], cnt = deg[i];
    float m = -1e30f, d = 0.f, acc = 0.f;
    for (int j = 0; j < cnt; ++j) {
        int src = eord[start + j];
        float xlv = xl[(size_t)src * D2 + t];
        float v = xlv + xrv;
        v = v > 0.f ? v : SLOPE * v;
        float lg = attv * v;
        lg += __shfl_xor(lg, 32, 64);
        lg += __shfl_xor(lg, 16, 64);
        lg += __shfl_xor(lg,  8, 64);
        lg += __shfl_xor(lg,  4, 64);
        lg += __shfl_xor(lg,  2, 64);
        lg += __shfl_xor(lg,  1, 64);
        if (lg > m) { float sc = __expf(m - lg); d *= sc; acc *= sc; m = lg; }
        float ex = __expf(lg - m);
        d += ex;
        acc += ex * xlv;
    }
    sh[t] = acc / d;
    __syncthreads();
    float v = 0.f;
    if (t < C2) {
        v = 0.25f * (sh[t] + sh[t + 64] + sh[t + 128] + sh[t + 192]) + b2[t];
        v = v > 0.f ? v : 0.f;
    }
    __syncthreads();
    if (t < C2) sh[t] = v;
    __syncthreads();
    if (t < 5) {
        float a = b3[t];
#pragma unroll 8
        for (int c = 0; c < C2; ++c) a += sh[c] * W3[c * 5 + t];
        out[(size_t)i * 5 + t] = 1.f / (1.f + __expf(-a));
    }
}

extern "C" void kernel_launch(void* const* d_in, const int* in_sizes, int n_in,
                              void* d_out, int out_size, void* d_ws, size_t ws_size,
                              hipStream_t stream) {
    const float* x     = (const float*)d_in[0];
    const int*   ei    = (const int*)d_in[1];
    const float* lb    = (const float*)d_in[2];
    const float* ub    = (const float*)d_in[3];
    const float* W1l   = (const float*)d_in[4];
    const float* b1l   = (const float*)d_in[5];
    const float* W1r   = (const float*)d_in[6];
    const float* b1r   = (const float*)d_in[7];
    const float* att1  = (const float*)d_in[8];
    const float* bias1 = (const float*)d_in[9];
    const float* W2l   = (const float*)d_in[10];
    const float* b2l   = (const float*)d_in[11];
    const float* W2r   = (const float*)d_in[12];
    const float* b2r   = (const float*)d_in[13];
    const float* att2  = (const float*)d_in[14];
    const float* bias2 = (const float*)d_in[15];
    const float* W3    = (const float*)d_in[16];
    const float* b3    = (const float*)d_in[17];

    int n  = in_sizes[0] / CIN;
    int E  = in_sizes[1] / 2;
    int ET = E + n;
    int nb = (n + 255) / 256;

    char* ws = (char*)d_ws;
    size_t off = 0;
    auto alloc = [&](size_t nbytes) {
        void* p = ws + off;
        off += (nbytes + 255) & ~(size_t)255;
        return p;
    };
    float* R0   = (float*)alloc((size_t)n * D2 * 4);  // xl1|xr1, later xl2
    float* h1   = (float*)alloc((size_t)n * D1 * 4);
    float* xr2  = (float*)alloc((size_t)n * D2 * 4);
    int*   deg  = (int*)alloc((size_t)n * 4);
    int*   cur  = (int*)alloc((size_t)n * 4);
    int*   rp   = (int*)alloc((size_t)n * 4);
    int*   bsum = (int*)alloc(256 * 4);
    int*   eord = (int*)alloc((size_t)ET * 4);
    float* xl1 = R0;
    float* xr1 = R0 + (size_t)n * D1;
    float* xl2 = R0;

    // ---- CSR build (shared by both layers) ----
    hipMemsetAsync(deg, 0, (size_t)n * 4, stream);
    hipMemsetAsync(cur, 0, (size_t)n * 4, stream);
    k_hist<<<(ET + 255) / 256, 256, 0, stream>>>(ei, E, ET, deg);
    k_scan_block<<<nb, 256, 0, stream>>>(deg, rp, bsum, n);
    k_scan_top<<<1, 256, 0, stream>>>(bsum, nb);
    k_scan_add<<<nb, 256, 0, stream>>>(rp, bsum, n);
    k_fill<<<(ET + 255) / 256, 256, 0, stream>>>(ei, E, ET, rp, cur, eord);

    // ---- layer 1 ----
    k_lin1<<<n, D1, 0, stream>>>(x, lb, ub, W1l, b1l, W1r, b1r, xl1, xr1);
    k_agg1<<<n, D1, 0, stream>>>(xl1, xr1, att1, bias1, rp, deg, eord, h1);

    // ---- layer 2 ----
    k_lin2<<<n, D2, 0, stream>>>(h1, W2l, b2l, W2r, b2r, xl2, xr2);
    k_agg2<<<n, D2, 0, stream>>>(xl2, xr2, att2, bias2, W3, b3, rp, deg, eord,
                                 (float*)d_out);
}

// Round 3
// 217.751 us; speedup vs baseline: 10.6965x; 2.8245x over previous
//
#include <hip/hip_runtime.h>

#define H 4
#define C1 32
#define D1 128
#define C2 64
#define D2 256
#define CIN 16
#define SLOPE 0.2f

__device__ __forceinline__ float bf2f(unsigned short u) {
    return __uint_as_float(((unsigned int)u) << 16);
}
__device__ __forceinline__ unsigned short f2bf(float f) {
    unsigned int u = __float_as_uint(f);
    u += 0x7FFFu + ((u >> 16) & 1u);
    return (unsigned short)(u >> 16);
}

// ============ CSR build ============
__global__ void k_hist(const int* __restrict__ ei, int E, int ET,
                       int* __restrict__ deg) {
    int idx = blockIdx.x * blockDim.x + threadIdx.x;
    if (idx >= ET) return;
    int dst = (idx < E) ? ei[E + idx] : idx - E;
    atomicAdd(&deg[dst], 1);
}

__global__ void k_scan_block(const int* __restrict__ deg, int* __restrict__ rp,
                             int* __restrict__ bsum, int n) {
    __shared__ int s[256];
    int t = threadIdx.x, idx = blockIdx.x * 256 + t;
    int v = (idx < n) ? deg[idx] : 0;
    s[t] = v; __syncthreads();
    for (int off = 1; off < 256; off <<= 1) {
        int add = (t >= off) ? s[t - off] : 0;
        __syncthreads();
        s[t] += add;
        __syncthreads();
    }
    if (idx < n) rp[idx] = s[t] - v;
    if (t == 255) bsum[blockIdx.x] = s[255];
}

__global__ void k_scan_top(int* __restrict__ bsum, int nb) {
    __shared__ int s[256];
    int t = threadIdx.x;
    int v = (t < nb) ? bsum[t] : 0;
    s[t] = v; __syncthreads();
    for (int off = 1; off < 256; off <<= 1) {
        int add = (t >= off) ? s[t - off] : 0;
        __syncthreads();
        s[t] += add;
        __syncthreads();
    }
    if (t < nb) bsum[t] = s[t] - v;
}

__global__ void k_scan_add(int* __restrict__ rp, const int* __restrict__ bsum, int n) {
    int idx = blockIdx.x * blockDim.x + threadIdx.x;
    if (idx < n) rp[idx] += bsum[idx >> 8];
}

__global__ void k_fill(const int* __restrict__ ei, int E, int ET,
                       const int* __restrict__ rp, int* __restrict__ cur,
                       int* __restrict__ eord) {
    int idx = blockIdx.x * blockDim.x + threadIdx.x;
    if (idx >= ET) return;
    int src, dst;
    if (idx < E) { src = ei[idx]; dst = ei[E + idx]; }
    else         { src = dst = idx - E; }
    int pos = atomicAdd(&cur[dst], 1);
    eord[rp[dst] + pos] = src;
}

// ============ layer-1 linear: 16 nodes/block, weights staged in LDS ============
__global__ __launch_bounds__(256) void k_lin1(
        const float* __restrict__ x, const float* __restrict__ lb,
        const float* __restrict__ ub,
        const float* __restrict__ Wl, const float* __restrict__ bl,
        const float* __restrict__ Wr, const float* __restrict__ br,
        unsigned short* __restrict__ xl, float* __restrict__ xr, int n) {
    __shared__ float Wls[CIN][D1];
    __shared__ float Wrs[CIN][D1];
    __shared__ float ys[16][CIN];
    int t = threadIdx.x;
    int i0 = blockIdx.x * 16;
#pragma unroll
    for (int i = 0; i < 8; ++i) {
        int flat = t + 256 * i;       // over [16][128]
        int k = flat >> 7, c = flat & 127;
        Wls[k][c] = Wl[k * D1 + c];
        Wrs[k][c] = Wr[k * D1 + c];
    }
    {
        int node = t >> 4, k = t & 15;
        int gi = i0 + node;
        float xv = (gi < n) ? x[(size_t)gi * CIN + k] : 0.f;
        ys[node][k] = (xv - lb[k]) / (ub[k] - lb[k]);
    }
    __syncthreads();
    int c = t & 127;
    bool left = t < 128;
    const float (*Ws)[D1] = left ? Wls : Wrs;
    float bias = left ? bl[c] : br[c];
    for (int j = 0; j < 16; ++j) {
        float acc = bias;
#pragma unroll
        for (int k = 0; k < CIN; ++k) acc += ys[j][k] * Ws[k][c];
        int gi = i0 + j;
        if (gi < n) {
            if (left) xl[(size_t)gi * D1 + c] = f2bf(acc);
            else      xr[(size_t)gi * D1 + c] = acc;
        }
    }
}

// ============ layer-2 linear as tiled GEMM ============
// M=n, K=128, N=512 (Wl|Wr). BM=128, BN=128 per block, 256 thr, 8x8 micro.
// grid.y: 0,1 -> Wl cols [0,128),[128,256) -> xl (bf16); 2,3 -> Wr -> xr (f32)
__global__ __launch_bounds__(256) void k_lin2(
        const float* __restrict__ h1,
        const float* __restrict__ Wl, const float* __restrict__ bl,
        const float* __restrict__ Wr, const float* __restrict__ br,
        unsigned short* __restrict__ xl, float* __restrict__ xr, int n) {
    __shared__ float As[32][132];   // transposed A chunk [k][m]
    __shared__ float Bs[32][128];
    int t = threadIdx.x;
    int tx = t & 15, ty = t >> 4;
    int row0 = blockIdx.x * 128;
    int NT = blockIdx.y;
    const float* W = (NT < 2) ? Wl : Wr;
    const float* bias = (NT < 2) ? bl : br;
    int nc0 = (NT & 1) * 128;
    float acc[8][8];
#pragma unroll
    for (int u = 0; u < 8; ++u)
#pragma unroll
        for (int v = 0; v < 8; ++v) acc[u][v] = 0.f;

    for (int kc = 0; kc < 4; ++kc) {
#pragma unroll
        for (int i = 0; i < 4; ++i) {
            int flat = t + 256 * i;    // [128 rows][8 k-quads]
            int row = flat >> 3, q = flat & 7;
            float4 vA = make_float4(0.f, 0.f, 0.f, 0.f);
            if (row0 + row < n)
                vA = *(const float4*)(h1 + (size_t)(row0 + row) * D1 + kc * 32 + q * 4);
            As[q * 4 + 0][row] = vA.x;
            As[q * 4 + 1][row] = vA.y;
            As[q * 4 + 2][row] = vA.z;
            As[q * 4 + 3][row] = vA.w;
        }
#pragma unroll
        for (int i = 0; i < 4; ++i) {
            int flat = t + 256 * i;    // [32 k][32 col-quads]
            int k = flat >> 5, q = flat & 31;
            float4 vB = *(const float4*)(W + (size_t)(kc * 32 + k) * D2 + nc0 + q * 4);
            *(float4*)&Bs[k][q * 4] = vB;
        }
        __syncthreads();
#pragma unroll
        for (int k = 0; k < 32; ++k) {
            float4 A0 = *(const float4*)&As[k][ty * 8];
            float4 A1 = *(const float4*)&As[k][ty * 8 + 4];
            float4 B0 = *(const float4*)&Bs[k][tx * 4];
            float4 B1 = *(const float4*)&Bs[k][tx * 4 + 64];
            float a_[8] = {A0.x, A0.y, A0.z, A0.w, A1.x, A1.y, A1.z, A1.w};
            float b_[8] = {B0.x, B0.y, B0.z, B0.w, B1.x, B1.y, B1.z, B1.w};
#pragma unroll
            for (int u = 0; u < 8; ++u)
#pragma unroll
                for (int v = 0; v < 8; ++v) acc[u][v] += a_[u] * b_[v];
        }
        __syncthreads();
    }

#pragma unroll
    for (int u = 0; u < 8; ++u) {
        int row = row0 + ty * 8 + u;
        if (row >= n) continue;
        int cb = nc0 + tx * 4;
        int cb2 = cb + 64;
        float o0 = acc[u][0] + bias[cb + 0];
        float o1 = acc[u][1] + bias[cb + 1];
        float o2 = acc[u][2] + bias[cb + 2];
        float o3 = acc[u][3] + bias[cb + 3];
        float p0 = acc[u][4] + bias[cb2 + 0];
        float p1 = acc[u][5] + bias[cb2 + 1];
        float p2 = acc[u][6] + bias[cb2 + 2];
        float p3 = acc[u][7] + bias[cb2 + 3];
        if (NT < 2) {
            ushort4 s0; s0.x = f2bf(o0); s0.y = f2bf(o1); s0.z = f2bf(o2); s0.w = f2bf(o3);
            ushort4 s1; s1.x = f2bf(p0); s1.y = f2bf(p1); s1.z = f2bf(p2); s1.w = f2bf(p3);
            *(ushort4*)(xl + (size_t)row * D2 + cb)  = s0;
            *(ushort4*)(xl + (size_t)row * D2 + cb2) = s1;
        } else {
            *(float4*)(xr + (size_t)row * D2 + cb)  = make_float4(o0, o1, o2, o3);
            *(float4*)(xr + (size_t)row * D2 + cb2) = make_float4(p0, p1, p2, p3);
        }
    }
}

// ============ fused GATv2 aggregation, layer 1 ============
// 64 threads = 2 nodes (32 lanes each); lane handles 4 comps (8B bf16x4 loads);
// head = 8-lane group; online softmax; 2-edge unroll.
__global__ __launch_bounds__(64) void k_agg1(
        const unsigned short* __restrict__ xl, const float* __restrict__ xr,
        const float* __restrict__ att, const float* __restrict__ bias,
        const int* __restrict__ rp, const int* __restrict__ deg,
        const int* __restrict__ eord, float* __restrict__ h1, int n) {
    int t = threadIdx.x;
    int node = blockIdx.x * 2 + (t >> 5);
    int l = t & 31;
    int nd = (node < n) ? node : n - 1;
    float4 xrv = *(const float4*)(xr + (size_t)nd * D1 + 4 * l);
    float4 av  = *(const float4*)(att + 4 * l);
    int start = rp[nd];
    int cnt = (node < n) ? deg[nd] : 0;
    float m = -1e30f, d = 0.f, a0 = 0.f, a1 = 0.f, a2 = 0.f, a3 = 0.f;
    for (int j = 0; j < cnt; j += 2) {
        bool two = (j + 1 < cnt);
        int s0 = eord[start + j];
        int s1 = two ? eord[start + j + 1] : s0;
        ushort4 u0 = *(const ushort4*)(xl + (size_t)s0 * D1 + 4 * l);
        ushort4 u1 = *(const ushort4*)(xl + (size_t)s1 * D1 + 4 * l);
        float x00 = bf2f(u0.x), x01 = bf2f(u0.y), x02 = bf2f(u0.z), x03 = bf2f(u0.w);
        float x10 = bf2f(u1.x), x11 = bf2f(u1.y), x12 = bf2f(u1.z), x13 = bf2f(u1.w);
        float v, lg0, lg1;
        v = x00 + xrv.x; v = v > 0.f ? v : SLOPE * v; lg0  = av.x * v;
        v = x01 + xrv.y; v = v > 0.f ? v : SLOPE * v; lg0 += av.y * v;
        v = x02 + xrv.z; v = v > 0.f ? v : SLOPE * v; lg0 += av.z * v;
        v = x03 + xrv.w; v = v > 0.f ? v : SLOPE * v; lg0 += av.w * v;
        v = x10 + xrv.x; v = v > 0.f ? v : SLOPE * v; lg1  = av.x * v;
        v = x11 + xrv.y; v = v > 0.f ? v : SLOPE * v; lg1 += av.y * v;
        v = x12 + xrv.z; v = v > 0.f ? v : SLOPE * v; lg1 += av.z * v;
        v = x13 + xrv.w; v = v > 0.f ? v : SLOPE * v; lg1 += av.w * v;
        lg0 += __shfl_xor(lg0, 4); lg1 += __shfl_xor(lg1, 4);
        lg0 += __shfl_xor(lg0, 2); lg1 += __shfl_xor(lg1, 2);
        lg0 += __shfl_xor(lg0, 1); lg1 += __shfl_xor(lg1, 1);
        float mx = two ? fmaxf(lg0, lg1) : lg0;
        if (mx > m) {
            float sc = __expf(m - mx);
            d *= sc; a0 *= sc; a1 *= sc; a2 *= sc; a3 *= sc;
            m = mx;
        }
        float e0 = __expf(lg0 - m);
        float e1 = two ? __expf(lg1 - m) : 0.f;
        d += e0 + e1;
        a0 += e0 * x00 + e1 * x10;
        a1 += e0 * x01 + e1 * x11;
        a2 += e0 * x02 + e1 * x12;
        a3 += e0 * x03 + e1 * x13;
    }
    if (node < n) {
        float inv = 1.f / d;
        float4 o;
        o.x = a0 * inv + bias[4 * l + 0]; o.x = o.x > 0.f ? o.x : 0.f;
        o.y = a1 * inv + bias[4 * l + 1]; o.y = o.y > 0.f ? o.y : 0.f;
        o.z = a2 * inv + bias[4 * l + 2]; o.z = o.z > 0.f ? o.z : 0.f;
        o.w = a3 * inv + bias[4 * l + 3]; o.w = o.w > 0.f ? o.w : 0.f;
        *(float4*)(h1 + (size_t)node * D1 + 4 * l) = o;
    }
}

// ============ fused GATv2 aggregation + head, layer 2 ============
// 64 threads = 1 node; lane handles 4 comps; head = 16-lane group.
__global__ __launch_bounds__(64) void k_agg2(
        const unsigned short* __restrict__ xl, const float* __restrict__ xr,
        const float* __restrict__ att, const float* __restrict__ b2,
        const float* __restrict__ W3, const float* __restrict__ b3,
        const int* __restrict__ rp, const int* __restrict__ deg,
        const int* __restrict__ eord, float* __restrict__ out) {
    __shared__ float sh[D2 + C2];
    int t = threadIdx.x;
    int node = blockIdx.x;
    float4 xrv = *(const float4*)(xr + (size_t)node * D2 + 4 * t);
    float4 av  = *(const float4*)(att + 4 * t);
    int start = rp[node];
    int cnt = deg[node];
    float m = -1e30f, d = 0.f, a0 = 0.f, a1 = 0.f, a2 = 0.f, a3 = 0.f;
    for (int j = 0; j < cnt; j += 2) {
        bool two = (j + 1 < cnt);
        int s0 = eord[start + j];
        int s1 = two ? eord[start + j + 1] : s0;
        ushort4 u0 = *(const ushort4*)(xl + (size_t)s0 * D2 + 4 * t);
        ushort4 u1 = *(const ushort4*)(xl + (size_t)s1 * D2 + 4 * t);
        float x00 = bf2f(u0.x), x01 = bf2f(u0.y), x02 = bf2f(u0.z), x03 = bf2f(u0.w);
        float x10 = bf2f(u1.x), x11 = bf2f(u1.y), x12 = bf2f(u1.z), x13 = bf2f(u1.w);
        float v, lg0, lg1;
        v = x00 + xrv.x; v = v > 0.f ? v : SLOPE * v; lg0  = av.x * v;
        v = x01 + xrv.y; v = v > 0.f ? v : SLOPE * v; lg0 += av.y * v;
        v = x02 + xrv.z; v = v > 0.f ? v : SLOPE * v; lg0 += av.z * v;
        v = x03 + xrv.w; v = v > 0.f ? v : SLOPE * v; lg0 += av.w * v;
        v = x10 + xrv.x; v = v > 0.f ? v : SLOPE * v; lg1  = av.x * v;
        v = x11 + xrv.y; v = v > 0.f ? v : SLOPE * v; lg1 += av.y * v;
        v = x12 + xrv.z; v = v > 0.f ? v : SLOPE * v; lg1 += av.z * v;
        v = x13 + xrv.w; v = v > 0.f ? v : SLOPE * v; lg1 += av.w * v;
        lg0 += __shfl_xor(lg0, 8); lg1 += __shfl_xor(lg1, 8);
        lg0 += __shfl_xor(lg0, 4); lg1 += __shfl_xor(lg1, 4);
        lg0 += __shfl_xor(lg0, 2); lg1 += __shfl_xor(lg1, 2);
        lg0 += __shfl_xor(lg0, 1); lg1 += __shfl_xor(lg1, 1);
        float mx = two ? fmaxf(lg0, lg1) : lg0;
        if (mx > m) {
            float sc = __expf(m - mx);
            d *= sc; a0 *= sc; a1 *= sc; a2 *= sc; a3 *= sc;
            m = mx;
        }
        float e0 = __expf(lg0 - m);
        float e1 = two ? __expf(lg1 - m) : 0.f;
        d += e0 + e1;
        a0 += e0 * x00 + e1 * x10;
        a1 += e0 * x01 + e1 * x11;
        a2 += e0 * x02 + e1 * x12;
        a3 += e0 * x03 + e1 * x13;
    }
    float inv = 1.f / d;
    *(float4*)&sh[4 * t] = make_float4(a0 * inv, a1 * inv, a2 * inv, a3 * inv);
    __syncthreads();
    float v = 0.25f * (sh[t] + sh[t + 64] + sh[t + 128] + sh[t + 192]) + b2[t];
    sh[D2 + t] = v > 0.f ? v : 0.f;
    __syncthreads();
    if (t < 5) {
        float a = b3[t];
#pragma unroll 8
        for (int c = 0; c < C2; ++c) a += sh[D2 + c] * W3[c * 5 + t];
        out[(size_t)node * 5 + t] = 1.f / (1.f + __expf(-a));
    }
}

extern "C" void kernel_launch(void* const* d_in, const int* in_sizes, int n_in,
                              void* d_out, int out_size, void* d_ws, size_t ws_size,
                              hipStream_t stream) {
    const float* x     = (const float*)d_in[0];
    const int*   ei    = (const int*)d_in[1];
    const float* lb    = (const float*)d_in[2];
    const float* ub    = (const float*)d_in[3];
    const float* W1l   = (const float*)d_in[4];
    const float* b1l   = (const float*)d_in[5];
    const float* W1r   = (const float*)d_in[6];
    const float* b1r   = (const float*)d_in[7];
    const float* att1  = (const float*)d_in[8];
    const float* bias1 = (const float*)d_in[9];
    const float* W2l   = (const float*)d_in[10];
    const float* b2l   = (const float*)d_in[11];
    const float* W2r   = (const float*)d_in[12];
    const float* b2r   = (const float*)d_in[13];
    const float* att2  = (const float*)d_in[14];
    const float* bias2 = (const float*)d_in[15];
    const float* W3    = (const float*)d_in[16];
    const float* b3    = (const float*)d_in[17];

    int n  = in_sizes[0] / CIN;
    int E  = in_sizes[1] / 2;
    int ET = E + n;
    int nb = (n + 255) / 256;

    char* ws = (char*)d_ws;
    size_t off = 0;
    auto alloc = [&](size_t nbytes) {
        void* p = ws + off;
        off += (nbytes + 255) & ~(size_t)255;
        return p;
    };
    unsigned short* xl1 = (unsigned short*)alloc((size_t)n * D1 * 2);
    float*          xr1 = (float*)alloc((size_t)n * D1 * 4);
    float*          h1  = (float*)alloc((size_t)n * D1 * 4);
    unsigned short* xl2 = (unsigned short*)alloc((size_t)n * D2 * 2);
    float*          xr2 = (float*)alloc((size_t)n * D2 * 4);
    int* deg  = (int*)alloc((size_t)n * 4);
    int* cur  = (int*)alloc((size_t)n * 4);
    int* rp   = (int*)alloc((size_t)n * 4);
    int* bsum = (int*)alloc(256 * 4);
    int* eord = (int*)alloc((size_t)ET * 4);

    // ---- CSR build ----
    hipMemsetAsync(deg, 0, (size_t)n * 4, stream);
    hipMemsetAsync(cur, 0, (size_t)n * 4, stream);
    k_hist<<<(ET + 255) / 256, 256, 0, stream>>>(ei, E, ET, deg);
    k_scan_block<<<nb, 256, 0, stream>>>(deg, rp, bsum, n);
    k_scan_top<<<1, 256, 0, stream>>>(bsum, nb);
    k_scan_add<<<nb, 256, 0, stream>>>(rp, bsum, n);
    k_fill<<<(ET + 255) / 256, 256, 0, stream>>>(ei, E, ET, rp, cur, eord);

    // ---- layer 1 ----
    k_lin1<<<(n + 15) / 16, 256, 0, stream>>>(x, lb, ub, W1l, b1l, W1r, b1r,
                                              xl1, xr1, n);
    k_agg1<<<(n + 1) / 2, 64, 0, stream>>>(xl1, xr1, att1, bias1, rp, deg,
                                           eord, h1, n);

    // ---- layer 2 ----
    dim3 g2((n + 127) / 128, 4);
    k_lin2<<<g2, 256, 0, stream>>>(h1, W2l, b2l, W2r, b2r, xl2, xr2, n);
    k_agg2<<<n, 64, 0, stream>>>(xl2, xr2, att2, bias2, W3, b3, rp, deg, eord,
                                 (float*)d_out);
}

// Round 4
// 217.326 us; speedup vs baseline: 10.7174x; 1.0020x over previous
//
#include <hip/hip_runtime.h>

#define H 4
#define C1 32
#define D1 128
#define C2 64
#define D2 256
#define CIN 16
#define SLOPE 0.2f
#define LOG2E 1.4426950408889634f

__device__ __forceinline__ float bf2f(unsigned short u) {
    return __uint_as_float(((unsigned int)u) << 16);
}
__device__ __forceinline__ unsigned short f2bf(float f) {
    unsigned int u = __float_as_uint(f);
    u += 0x7FFFu + ((u >> 16) & 1u);
    return (unsigned short)(u >> 16);
}

// ============ CSR build ============
__global__ void k_hist(const int* __restrict__ ei, int E, int ET,
                       int* __restrict__ deg) {
    int idx = blockIdx.x * blockDim.x + threadIdx.x;
    if (idx >= ET) return;
    int dst = (idx < E) ? ei[E + idx] : idx - E;
    atomicAdd(&deg[dst], 1);
}

__global__ void k_scan_block(const int* __restrict__ deg, int* __restrict__ rp,
                             int* __restrict__ bsum, int n) {
    __shared__ int s[256];
    int t = threadIdx.x, idx = blockIdx.x * 256 + t;
    int v = (idx < n) ? deg[idx] : 0;
    s[t] = v; __syncthreads();
    for (int off = 1; off < 256; off <<= 1) {
        int add = (t >= off) ? s[t - off] : 0;
        __syncthreads();
        s[t] += add;
        __syncthreads();
    }
    if (idx < n) rp[idx] = s[t] - v;
    if (t == 255) bsum[blockIdx.x] = s[255];
}

__global__ void k_scan_top(int* __restrict__ bsum, int nb) {
    __shared__ int s[256];
    int t = threadIdx.x;
    int v = (t < nb) ? bsum[t] : 0;
    s[t] = v; __syncthreads();
    for (int off = 1; off < 256; off <<= 1) {
        int add = (t >= off) ? s[t - off] : 0;
        __syncthreads();
        s[t] += add;
        __syncthreads();
    }
    if (t < nb) bsum[t] = s[t] - v;
}

__global__ void k_scan_add(int* __restrict__ rp, const int* __restrict__ bsum, int n) {
    int idx = blockIdx.x * blockDim.x + threadIdx.x;
    if (idx < n) rp[idx] += bsum[idx >> 8];
}

__global__ void k_fill(const int* __restrict__ ei, int E, int ET,
                       const int* __restrict__ rp, int* __restrict__ cur,
                       int* __restrict__ eord) {
    int idx = blockIdx.x * blockDim.x + threadIdx.x;
    if (idx >= ET) return;
    int src, dst;
    if (idx < E) { src = ei[idx]; dst = ei[E + idx]; }
    else         { src = dst = idx - E; }
    int pos = atomicAdd(&cur[dst], 1);
    eord[rp[dst] + pos] = src;
}

// ============ layer-1 linear: 16 nodes/block, weights staged in LDS ============
__global__ __launch_bounds__(256) void k_lin1(
        const float* __restrict__ x, const float* __restrict__ lb,
        const float* __restrict__ ub,
        const float* __restrict__ Wl, const float* __restrict__ bl,
        const float* __restrict__ Wr, const float* __restrict__ br,
        unsigned short* __restrict__ xl, float* __restrict__ xr, int n) {
    __shared__ float Wls[CIN][D1];
    __shared__ float Wrs[CIN][D1];
    __shared__ float ys[16][CIN];
    int t = threadIdx.x;
    int i0 = blockIdx.x * 16;
#pragma unroll
    for (int i = 0; i < 8; ++i) {
        int flat = t + 256 * i;
        int k = flat >> 7, c = flat & 127;
        Wls[k][c] = Wl[k * D1 + c];
        Wrs[k][c] = Wr[k * D1 + c];
    }
    {
        int node = t >> 4, k = t & 15;
        int gi = i0 + node;
        float xv = (gi < n) ? x[(size_t)gi * CIN + k] : 0.f;
        ys[node][k] = (xv - lb[k]) / (ub[k] - lb[k]);
    }
    __syncthreads();
    int c = t & 127;
    bool left = t < 128;
    const float (*Ws)[D1] = left ? Wls : Wrs;
    float bias = left ? bl[c] : br[c];
    for (int j = 0; j < 16; ++j) {
        float acc = bias;
#pragma unroll
        for (int k = 0; k < CIN; ++k) acc += ys[j][k] * Ws[k][c];
        int gi = i0 + j;
        if (gi < n) {
            if (left) xl[(size_t)gi * D1 + c] = f2bf(acc);
            else      xr[(size_t)gi * D1 + c] = acc;
        }
    }
}

// ============ layer-2 linear as tiled GEMM ============
__global__ __launch_bounds__(256) void k_lin2(
        const float* __restrict__ h1,
        const float* __restrict__ Wl, const float* __restrict__ bl,
        const float* __restrict__ Wr, const float* __restrict__ br,
        unsigned short* __restrict__ xl, float* __restrict__ xr, int n) {
    __shared__ float As[32][132];
    __shared__ float Bs[32][128];
    int t = threadIdx.x;
    int tx = t & 15, ty = t >> 4;
    int row0 = blockIdx.x * 128;
    int NT = blockIdx.y;
    const float* W = (NT < 2) ? Wl : Wr;
    const float* bias = (NT < 2) ? bl : br;
    int nc0 = (NT & 1) * 128;
    float acc[8][8];
#pragma unroll
    for (int u = 0; u < 8; ++u)
#pragma unroll
        for (int v = 0; v < 8; ++v) acc[u][v] = 0.f;

    for (int kc = 0; kc < 4; ++kc) {
#pragma unroll
        for (int i = 0; i < 4; ++i) {
            int flat = t + 256 * i;
            int row = flat >> 3, q = flat & 7;
            float4 vA = make_float4(0.f, 0.f, 0.f, 0.f);
            if (row0 + row < n)
                vA = *(const float4*)(h1 + (size_t)(row0 + row) * D1 + kc * 32 + q * 4);
            As[q * 4 + 0][row] = vA.x;
            As[q * 4 + 1][row] = vA.y;
            As[q * 4 + 2][row] = vA.z;
            As[q * 4 + 3][row] = vA.w;
        }
#pragma unroll
        for (int i = 0; i < 4; ++i) {
            int flat = t + 256 * i;
            int k = flat >> 5, q = flat & 31;
            float4 vB = *(const float4*)(W + (size_t)(kc * 32 + k) * D2 + nc0 + q * 4);
            *(float4*)&Bs[k][q * 4] = vB;
        }
        __syncthreads();
#pragma unroll
        for (int k = 0; k < 32; ++k) {
            float4 A0 = *(const float4*)&As[k][ty * 8];
            float4 A1 = *(const float4*)&As[k][ty * 8 + 4];
            float4 B0 = *(const float4*)&Bs[k][tx * 4];
            float4 B1 = *(const float4*)&Bs[k][tx * 4 + 64];
            float a_[8] = {A0.x, A0.y, A0.z, A0.w, A1.x, A1.y, A1.z, A1.w};
            float b_[8] = {B0.x, B0.y, B0.z, B0.w, B1.x, B1.y, B1.z, B1.w};
#pragma unroll
            for (int u = 0; u < 8; ++u)
#pragma unroll
                for (int v = 0; v < 8; ++v) acc[u][v] += a_[u] * b_[v];
        }
        __syncthreads();
    }

#pragma unroll
    for (int u = 0; u < 8; ++u) {
        int row = row0 + ty * 8 + u;
        if (row >= n) continue;
        int cb = nc0 + tx * 4;
        int cb2 = cb + 64;
        float o0 = acc[u][0] + bias[cb + 0];
        float o1 = acc[u][1] + bias[cb + 1];
        float o2 = acc[u][2] + bias[cb + 2];
        float o3 = acc[u][3] + bias[cb + 3];
        float p0 = acc[u][4] + bias[cb2 + 0];
        float p1 = acc[u][5] + bias[cb2 + 1];
        float p2 = acc[u][6] + bias[cb2 + 2];
        float p3 = acc[u][7] + bias[cb2 + 3];
        if (NT < 2) {
            ushort4 s0; s0.x = f2bf(o0); s0.y = f2bf(o1); s0.z = f2bf(o2); s0.w = f2bf(o3);
            ushort4 s1; s1.x = f2bf(p0); s1.y = f2bf(p1); s1.z = f2bf(p2); s1.w = f2bf(p3);
            *(ushort4*)(xl + (size_t)row * D2 + cb)  = s0;
            *(ushort4*)(xl + (size_t)row * D2 + cb2) = s1;
        } else {
            *(float4*)(xr + (size_t)row * D2 + cb)  = make_float4(o0, o1, o2, o3);
            *(float4*)(xr + (size_t)row * D2 + cb2) = make_float4(p0, p1, p2, p3);
        }
    }
}

// ============ fused GATv2 aggregation, layer 1 ============
// 256 thr = 8 nodes (32 lanes each), lane: 4 comps, head = 8-lane group.
// No max-subtraction (logits tiny); exp2 domain; 4-edge unroll.
__global__ __launch_bounds__(256) void k_agg1(
        const unsigned short* __restrict__ xl, const float* __restrict__ xr,
        const float* __restrict__ att, const float* __restrict__ bias,
        const int* __restrict__ rp, const int* __restrict__ deg,
        const int* __restrict__ eord, float* __restrict__ h1, int n) {
    int t = threadIdx.x;
    int node = blockIdx.x * 8 + (t >> 5);
    int l = t & 31;
    int nd = (node < n) ? node : n - 1;
    float4 xrv = *(const float4*)(xr + (size_t)nd * D1 + 4 * l);
    float4 av  = *(const float4*)(att + 4 * l);
    av.x *= LOG2E; av.y *= LOG2E; av.z *= LOG2E; av.w *= LOG2E;
    int start = rp[nd];
    int cnt = (node < n) ? deg[nd] : 0;
    float d = 0.f, a0 = 0.f, a1 = 0.f, a2 = 0.f, a3 = 0.f;
    for (int j = 0; j < cnt; j += 4) {
        int s0 = eord[start + j];
        int s1 = (j + 1 < cnt) ? eord[start + j + 1] : s0;
        int s2 = (j + 2 < cnt) ? eord[start + j + 2] : s0;
        int s3 = (j + 3 < cnt) ? eord[start + j + 3] : s0;
        ushort4 u0 = *(const ushort4*)(xl + (size_t)s0 * D1 + 4 * l);
        ushort4 u1 = *(const ushort4*)(xl + (size_t)s1 * D1 + 4 * l);
        ushort4 u2 = *(const ushort4*)(xl + (size_t)s2 * D1 + 4 * l);
        ushort4 u3 = *(const ushort4*)(xl + (size_t)s3 * D1 + 4 * l);
        float x00 = bf2f(u0.x), x01 = bf2f(u0.y), x02 = bf2f(u0.z), x03 = bf2f(u0.w);
        float x10 = bf2f(u1.x), x11 = bf2f(u1.y), x12 = bf2f(u1.z), x13 = bf2f(u1.w);
        float x20 = bf2f(u2.x), x21 = bf2f(u2.y), x22 = bf2f(u2.z), x23 = bf2f(u2.w);
        float x30 = bf2f(u3.x), x31 = bf2f(u3.y), x32 = bf2f(u3.z), x33 = bf2f(u3.w);
        float v, lg0, lg1, lg2, lg3;
        v = x00 + xrv.x; v = v > 0.f ? v : SLOPE * v; lg0  = av.x * v;
        v = x01 + xrv.y; v = v > 0.f ? v : SLOPE * v; lg0 += av.y * v;
        v = x02 + xrv.z; v = v > 0.f ? v : SLOPE * v; lg0 += av.z * v;
        v = x03 + xrv.w; v = v > 0.f ? v : SLOPE * v; lg0 += av.w * v;
        v = x10 + xrv.x; v = v > 0.f ? v : SLOPE * v; lg1  = av.x * v;
        v = x11 + xrv.y; v = v > 0.f ? v : SLOPE * v; lg1 += av.y * v;
        v = x12 + xrv.z; v = v > 0.f ? v : SLOPE * v; lg1 += av.z * v;
        v = x13 + xrv.w; v = v > 0.f ? v : SLOPE * v; lg1 += av.w * v;
        v = x20 + xrv.x; v = v > 0.f ? v : SLOPE * v; lg2  = av.x * v;
        v = x21 + xrv.y; v = v > 0.f ? v : SLOPE * v; lg2 += av.y * v;
        v = x22 + xrv.z; v = v > 0.f ? v : SLOPE * v; lg2 += av.z * v;
        v = x23 + xrv.w; v = v > 0.f ? v : SLOPE * v; lg2 += av.w * v;
        v = x30 + xrv.x; v = v > 0.f ? v : SLOPE * v; lg3  = av.x * v;
        v = x31 + xrv.y; v = v > 0.f ? v : SLOPE * v; lg3 += av.y * v;
        v = x32 + xrv.z; v = v > 0.f ? v : SLOPE * v; lg3 += av.z * v;
        v = x33 + xrv.w; v = v > 0.f ? v : SLOPE * v; lg3 += av.w * v;
        lg0 += __shfl_xor(lg0, 4); lg1 += __shfl_xor(lg1, 4);
        lg2 += __shfl_xor(lg2, 4); lg3 += __shfl_xor(lg3, 4);
        lg0 += __shfl_xor(lg0, 2); lg1 += __shfl_xor(lg1, 2);
        lg2 += __shfl_xor(lg2, 2); lg3 += __shfl_xor(lg3, 2);
        lg0 += __shfl_xor(lg0, 1); lg1 += __shfl_xor(lg1, 1);
        lg2 += __shfl_xor(lg2, 1); lg3 += __shfl_xor(lg3, 1);
        float e0 = exp2f(lg0);
        float e1 = (j + 1 < cnt) ? exp2f(lg1) : 0.f;
        float e2 = (j + 2 < cnt) ? exp2f(lg2) : 0.f;
        float e3 = (j + 3 < cnt) ? exp2f(lg3) : 0.f;
        d += (e0 + e1) + (e2 + e3);
        a0 += e0 * x00 + e1 * x10 + e2 * x20 + e3 * x30;
        a1 += e0 * x01 + e1 * x11 + e2 * x21 + e3 * x31;
        a2 += e0 * x02 + e1 * x12 + e2 * x22 + e3 * x32;
        a3 += e0 * x03 + e1 * x13 + e2 * x23 + e3 * x33;
    }
    if (node < n) {
        float inv = 1.f / d;
        float4 o;
        o.x = a0 * inv + bias[4 * l + 0]; o.x = o.x > 0.f ? o.x : 0.f;
        o.y = a1 * inv + bias[4 * l + 1]; o.y = o.y > 0.f ? o.y : 0.f;
        o.z = a2 * inv + bias[4 * l + 2]; o.z = o.z > 0.f ? o.z : 0.f;
        o.w = a3 * inv + bias[4 * l + 3]; o.w = o.w > 0.f ? o.w : 0.f;
        *(float4*)(h1 + (size_t)node * D1 + 4 * l) = o;
    }
}

// ============ fused GATv2 aggregation + head, layer 2 ============
// 256 thr = 4 nodes (64 lanes = 1 wave each); lane: 4 comps, head = 16-lane
// group. No max-subtraction; exp2 domain; 4-edge unroll; wave-local epilogue.
__global__ __launch_bounds__(256) void k_agg2(
        const unsigned short* __restrict__ xl, const float* __restrict__ xr,
        const float* __restrict__ att, const float* __restrict__ b2,
        const float* __restrict__ W3, const float* __restrict__ b3,
        const int* __restrict__ rp, const int* __restrict__ deg,
        const int* __restrict__ eord, float* __restrict__ out, int n) {
    int t = threadIdx.x;
    int node = blockIdx.x * 4 + (t >> 6);
    int l = t & 63;
    int nd = (node < n) ? node : n - 1;
    float4 xrv = *(const float4*)(xr + (size_t)nd * D2 + 4 * l);
    float4 av  = *(const float4*)(att + 4 * l);
    av.x *= LOG2E; av.y *= LOG2E; av.z *= LOG2E; av.w *= LOG2E;
    int start = rp[nd];
    int cnt = (node < n) ? deg[nd] : 0;
    float d = 0.f, a0 = 0.f, a1 = 0.f, a2 = 0.f, a3 = 0.f;
    for (int j = 0; j < cnt; j += 4) {
        int s0 = eord[start + j];
        int s1 = (j + 1 < cnt) ? eord[start + j + 1] : s0;
        int s2 = (j + 2 < cnt) ? eord[start + j + 2] : s0;
        int s3 = (j + 3 < cnt) ? eord[start + j + 3] : s0;
        ushort4 u0 = *(const ushort4*)(xl + (size_t)s0 * D2 + 4 * l);
        ushort4 u1 = *(const ushort4*)(xl + (size_t)s1 * D2 + 4 * l);
        ushort4 u2 = *(const ushort4*)(xl + (size_t)s2 * D2 + 4 * l);
        ushort4 u3 = *(const ushort4*)(xl + (size_t)s3 * D2 + 4 * l);
        float x00 = bf2f(u0.x), x01 = bf2f(u0.y), x02 = bf2f(u0.z), x03 = bf2f(u0.w);
        float x10 = bf2f(u1.x), x11 = bf2f(u1.y), x12 = bf2f(u1.z), x13 = bf2f(u1.w);
        float x20 = bf2f(u2.x), x21 = bf2f(u2.y), x22 = bf2f(u2.z), x23 = bf2f(u2.w);
        float x30 = bf2f(u3.x), x31 = bf2f(u3.y), x32 = bf2f(u3.z), x33 = bf2f(u3.w);
        float v, lg0, lg1, lg2, lg3;
        v = x00 + xrv.x; v = v > 0.f ? v : SLOPE * v; lg0  = av.x * v;
        v = x01 + xrv.y; v = v > 0.f ? v : SLOPE * v; lg0 += av.y * v;
        v = x02 + xrv.z; v = v > 0.f ? v : SLOPE * v; lg0 += av.z * v;
        v = x03 + xrv.w; v = v > 0.f ? v : SLOPE * v; lg0 += av.w * v;
        v = x10 + xrv.x; v = v > 0.f ? v : SLOPE * v; lg1  = av.x * v;
        v = x11 + xrv.y; v = v > 0.f ? v : SLOPE * v; lg1 += av.y * v;
        v = x12 + xrv.z; v = v > 0.f ? v : SLOPE * v; lg1 += av.z * v;
        v = x13 + xrv.w; v = v > 0.f ? v : SLOPE * v; lg1 += av.w * v;
        v = x20 + xrv.x; v = v > 0.f ? v : SLOPE * v; lg2  = av.x * v;
        v = x21 + xrv.y; v = v > 0.f ? v : SLOPE * v; lg2 += av.y * v;
        v = x22 + xrv.z; v = v > 0.f ? v : SLOPE * v; lg2 += av.z * v;
        v = x23 + xrv.w; v = v > 0.f ? v : SLOPE * v; lg2 += av.w * v;
        v = x30 + xrv.x; v = v > 0.f ? v : SLOPE * v; lg3  = av.x * v;
        v = x31 + xrv.y; v = v > 0.f ? v : SLOPE * v; lg3 += av.y * v;
        v = x32 + xrv.z; v = v > 0.f ? v : SLOPE * v; lg3 += av.z * v;
        v = x33 + xrv.w; v = v > 0.f ? v : SLOPE * v; lg3 += av.w * v;
        lg0 += __shfl_xor(lg0, 8); lg1 += __shfl_xor(lg1, 8);
        lg2 += __shfl_xor(lg2, 8); lg3 += __shfl_xor(lg3, 8);
        lg0 += __shfl_xor(lg0, 4); lg1 += __shfl_xor(lg1, 4);
        lg2 += __shfl_xor(lg2, 4); lg3 += __shfl_xor(lg3, 4);
        lg0 += __shfl_xor(lg0, 2); lg1 += __shfl_xor(lg1, 2);
        lg2 += __shfl_xor(lg2, 2); lg3 += __shfl_xor(lg3, 2);
        lg0 += __shfl_xor(lg0, 1); lg1 += __shfl_xor(lg1, 1);
        lg2 += __shfl_xor(lg2, 1); lg3 += __shfl_xor(lg3, 1);
        float e0 = exp2f(lg0);
        float e1 = (j + 1 < cnt) ? exp2f(lg1) : 0.f;
        float e2 = (j + 2 < cnt) ? exp2f(lg2) : 0.f;
        float e3 = (j + 3 < cnt) ? exp2f(lg3) : 0.f;
        d += (e0 + e1) + (e2 + e3);
        a0 += e0 * x00 + e1 * x10 + e2 * x20 + e3 * x30;
        a1 += e0 * x01 + e1 * x11 + e2 * x21 + e3 * x31;
        a2 += e0 * x02 + e1 * x12 + e2 * x22 + e3 * x32;
        a3 += e0 * x03 + e1 * x13 + e2 * x23 + e3 * x33;
    }
    // wave-local epilogue: head mean -> bias -> relu -> W3 -> sigmoid
    float inv = 1.f / d;
    float v0 = a0 * inv, v1 = a1 * inv, v2 = a2 * inv, v3 = a3 * inv;
    // sum the same within-head comp across the 4 heads (lanes l, l^16, l^32, l^48)
    v0 += __shfl_xor(v0, 16); v1 += __shfl_xor(v1, 16);
    v2 += __shfl_xor(v2, 16); v3 += __shfl_xor(v3, 16);
    v0 += __shfl_xor(v0, 32); v1 += __shfl_xor(v1, 32);
    v2 += __shfl_xor(v2, 32); v3 += __shfl_xor(v3, 32);
    int c0 = 4 * (l & 15);
    v0 = 0.25f * v0 + b2[c0 + 0]; v0 = v0 > 0.f ? v0 : 0.f;
    v1 = 0.25f * v1 + b2[c0 + 1]; v1 = v1 > 0.f ? v1 : 0.f;
    v2 = 0.25f * v2 + b2[c0 + 2]; v2 = v2 > 0.f ? v2 : 0.f;
    v3 = 0.25f * v3 + b2[c0 + 3]; v3 = v3 > 0.f ? v3 : 0.f;
    // 64->5 matvec: per-lane partials over its 4 comps, reduce over 16-group
    float p0, p1, p2, p3, p4;
    {
        const float* w0 = W3 + (c0 + 0) * 5;
        const float* w1 = W3 + (c0 + 1) * 5;
        const float* w2 = W3 + (c0 + 2) * 5;
        const float* w3 = W3 + (c0 + 3) * 5;
        p0 = v0 * w0[0] + v1 * w1[0] + v2 * w2[0] + v3 * w3[0];
        p1 = v0 * w0[1] + v1 * w1[1] + v2 * w2[1] + v3 * w3[1];
        p2 = v0 * w0[2] + v1 * w1[2] + v2 * w2[2] + v3 * w3[2];
        p3 = v0 * w0[3] + v1 * w1[3] + v2 * w2[3] + v3 * w3[3];
        p4 = v0 * w0[4] + v1 * w1[4] + v2 * w2[4] + v3 * w3[4];
    }
#pragma unroll
    for (int off = 1; off < 16; off <<= 1) {
        p0 += __shfl_xor(p0, off); p1 += __shfl_xor(p1, off);
        p2 += __shfl_xor(p2, off); p3 += __shfl_xor(p3, off);
        p4 += __shfl_xor(p4, off);
    }
    if (l == 0 && node < n) {
        float* o = out + (size_t)node * 5;
        o[0] = 1.f / (1.f + __expf(-(p0 + b3[0])));
        o[1] = 1.f / (1.f + __expf(-(p1 + b3[1])));
        o[2] = 1.f / (1.f + __expf(-(p2 + b3[2])));
        o[3] = 1.f / (1.f + __expf(-(p3 + b3[3])));
        o[4] = 1.f / (1.f + __expf(-(p4 + b3[4])));
    }
}

extern "C" void kernel_launch(void* const* d_in, const int* in_sizes, int n_in,
                              void* d_out, int out_size, void* d_ws, size_t ws_size,
                              hipStream_t stream) {
    const float* x     = (const float*)d_in[0];
    const int*   ei    = (const int*)d_in[1];
    const float* lb    = (const float*)d_in[2];
    const float* ub    = (const float*)d_in[3];
    const float* W1l   = (const float*)d_in[4];
    const float* b1l   = (const float*)d_in[5];
    const float* W1r   = (const float*)d_in[6];
    const float* b1r   = (const float*)d_in[7];
    const float* att1  = (const float*)d_in[8];
    const float* bias1 = (const float*)d_in[9];
    const float* W2l   = (const float*)d_in[10];
    const float* b2l   = (const float*)d_in[11];
    const float* W2r   = (const float*)d_in[12];
    const float* b2r   = (const float*)d_in[13];
    const float* att2  = (const float*)d_in[14];
    const float* bias2 = (const float*)d_in[15];
    const float* W3    = (const float*)d_in[16];
    const float* b3    = (const float*)d_in[17];

    int n  = in_sizes[0] / CIN;
    int E  = in_sizes[1] / 2;
    int ET = E + n;
    int nb = (n + 255) / 256;

    char* ws = (char*)d_ws;
    size_t off = 0;
    auto alloc = [&](size_t nbytes) {
        void* p = ws + off;
        off += (nbytes + 255) & ~(size_t)255;
        return p;
    };
    unsigned short* xl1 = (unsigned short*)alloc((size_t)n * D1 * 2);
    float*          xr1 = (float*)alloc((size_t)n * D1 * 4);
    float*          h1  = (float*)alloc((size_t)n * D1 * 4);
    unsigned short* xl2 = (unsigned short*)alloc((size_t)n * D2 * 2);
    float*          xr2 = (float*)alloc((size_t)n * D2 * 4);
    int* deg  = (int*)alloc((size_t)n * 4);
    int* cur  = (int*)alloc((size_t)n * 4);
    int* rp   = (int*)alloc((size_t)n * 4);
    int* bsum = (int*)alloc(256 * 4);
    int* eord = (int*)alloc((size_t)ET * 4);

    // ---- CSR build ----
    hipMemsetAsync(deg, 0, (size_t)n * 4, stream);
    hipMemsetAsync(cur, 0, (size_t)n * 4, stream);
    k_hist<<<(ET + 255) / 256, 256, 0, stream>>>(ei, E, ET, deg);
    k_scan_block<<<nb, 256, 0, stream>>>(deg, rp, bsum, n);
    k_scan_top<<<1, 256, 0, stream>>>(bsum, nb);
    k_scan_add<<<nb, 256, 0, stream>>>(rp, bsum, n);
    k_fill<<<(ET + 255) / 256, 256, 0, stream>>>(ei, E, ET, rp, cur, eord);

    // ---- layer 1 ----
    k_lin1<<<(n + 15) / 16, 256, 0, stream>>>(x, lb, ub, W1l, b1l, W1r, b1r,
                                              xl1, xr1, n);
    k_agg1<<<(n + 7) / 8, 256, 0, stream>>>(xl1, xr1, att1, bias1, rp, deg,
                                            eord, h1, n);

    // ---- layer 2 ----
    dim3 g2((n + 127) / 128, 4);
    k_lin2<<<g2, 256, 0, stream>>>(h1, W2l, b2l, W2r, b2r, xl2, xr2, n);
    k_agg2<<<(n + 3) / 4, 256, 0, stream>>>(xl2, xr2, att2, bias2, W3, b3,
                                            rp, deg, eord, (float*)d_out, n);
}